// Round 4
// baseline (521.999 us; speedup 1.0000x reference)
//
#include <hip/hip_runtime.h>

#define N_NODES 100000
#define DEG 16
#define NT16 6250             // 16-row tiles (100000/16)
#define NG64 1563             // 64-row groups (ceil)
#define NBLK 768              // 3 blocks/CU x 256 CUs -> all resident
#define MAGIC 0x0C0FFEEu

typedef __attribute__((ext_vector_type(8))) short short8;   // 8 bf16
typedef __attribute__((ext_vector_type(4))) float f32x4;

__device__ inline unsigned short f2bf(float f) {
    union { float f; unsigned u; } v; v.f = f;
    unsigned u = v.u;
    u += 0x7FFFu + ((u >> 16) & 1u);    // RNE
    return (unsigned short)(u >> 16);
}
__device__ inline unsigned pk2bf(float a, float b) {
    return (unsigned)f2bf(a) | ((unsigned)f2bf(b) << 16);
}
__device__ inline float bflo(unsigned u) {
    union { unsigned u; float f; } v; v.u = u << 16; return v.f;
}
__device__ inline float bfhi(unsigned u) {
    union { unsigned u; float f; } v; v.u = u & 0xFFFF0000u; return v.f;
}

__device__ inline void grid_bar(unsigned* bar, unsigned target) {
    __syncthreads();
    if (threadIdx.x == 0) {
        // wait for one-time init (handles 0xAA poison deterministically)
        while (__hip_atomic_load(&bar[0], __ATOMIC_ACQUIRE, __HIP_MEMORY_SCOPE_AGENT) != MAGIC)
            __builtin_amdgcn_s_sleep(1);
        __threadfence();   // release our phase writes to device scope
        __hip_atomic_fetch_add(&bar[1], 1u, __ATOMIC_ACQ_REL, __HIP_MEMORY_SCOPE_AGENT);
        while (__hip_atomic_load(&bar[1], __ATOMIC_ACQUIRE, __HIP_MEMORY_SCOPE_AGENT) < target)
            __builtin_amdgcn_s_sleep(1);
        __threadfence();
    }
    __syncthreads();
}

__global__ __launch_bounds__(256, 3) void gcn_fused(const float* __restrict__ X,
                                                    const float* __restrict__ W1,
                                                    const float* __restrict__ W2,
                                                    const float* __restrict__ vals,
                                                    const int* __restrict__ colind,
                                                    float* __restrict__ out,
                                                    unsigned* __restrict__ bar,
                                                    unsigned short* __restrict__ h,
                                                    unsigned short* __restrict__ o1)
{
    __shared__ unsigned short wfrag1[256 * 64];     // 32 KB, W1 B-fragments
    __shared__ unsigned short wfrag2[64 * 64];      //  8 KB, W2 B-fragments
    __shared__ unsigned short estage[4][16 * 72];   //  9 KB, per-wave scratch

    const int tid  = threadIdx.x;
    const int lane = tid & 63;
    const int wid  = tid >> 6;
    const int q    = lane >> 4;
    const int l16  = lane & 15;

    // --- one-time barrier init (block 0), hidden behind W staging ---
    if (blockIdx.x == 0 && tid == 0) {
        __hip_atomic_store(&bar[1], 0u, __ATOMIC_RELAXED, __HIP_MEMORY_SCOPE_AGENT);
        __hip_atomic_store(&bar[0], MAGIC, __ATOMIC_RELEASE, __HIP_MEMORY_SCOPE_AGENT);
    }

    // --- stage W1 and W2 into B-fragment order (once per block) ---
    // wfrag[((kb*4+ct)*64+ln)*8+j] = W[kb*32+(ln>>4)*8+j][ct*16+(ln&15)]
    for (int idx = tid; idx < 256 * 64; idx += 256) {
        int j  = idx & 7;
        int ln = (idx >> 3) & 63;
        int ct = (idx >> 9) & 3;
        int kb = idx >> 11;
        wfrag1[idx] = f2bf(W1[(kb * 32 + ((ln >> 4) << 3) + j) * 64 + ct * 16 + (ln & 15)]);
    }
    for (int idx = tid; idx < 64 * 64; idx += 256) {
        int j  = idx & 7;
        int ln = (idx >> 3) & 63;
        int ct = (idx >> 9) & 3;
        int kb = idx >> 11;
        wfrag2[idx] = f2bf(W2[(kb * 32 + ((ln >> 4) << 3) + j) * 64 + ct * 16 + (ln & 15)]);
    }
    __syncthreads();

    // =====================================================================
    // Phase 1: h = bf16(X @ W1).  No A-stage: coalesced loads + ds_bpermute
    // to rearrange into MFMA A-fragment layout.
    // Load mapping: lane s holds X[t*16 + (s>>2)][kb*32 + (s&3)*8 .. +7].
    // A-frag for lane t needs row=t&15, chunk=t>>4 -> source s=((t&15)<<2)|(t>>4).
    // =====================================================================
    const int bpidx = ((((lane & 15) << 2) | (lane >> 4)) << 2);
    for (int t = blockIdx.x * 4 + wid; t < NT16; t += NBLK * 4) {
        const float* xb = X + ((size_t)t * 16 + (lane >> 2)) * 256 + (lane & 3) * 8;
        f32x4 a0 = {0,0,0,0}, a1 = {0,0,0,0}, a2 = {0,0,0,0}, a3 = {0,0,0,0};
        #pragma unroll
        for (int kb = 0; kb < 8; ++kb) {
            float4 u0 = *(const float4*)(xb + kb * 32);
            float4 u1 = *(const float4*)(xb + kb * 32 + 4);
            int d0 = (int)pk2bf(u0.x, u0.y);
            int d1 = (int)pk2bf(u0.z, u0.w);
            int d2 = (int)pk2bf(u1.x, u1.y);
            int d3 = (int)pk2bf(u1.z, u1.w);
            union { int u[4]; short8 s; } uu;
            uu.u[0] = __builtin_amdgcn_ds_bpermute(bpidx, d0);
            uu.u[1] = __builtin_amdgcn_ds_bpermute(bpidx, d1);
            uu.u[2] = __builtin_amdgcn_ds_bpermute(bpidx, d2);
            uu.u[3] = __builtin_amdgcn_ds_bpermute(bpidx, d3);
            const short8* wp = (const short8*)&wfrag1[(size_t)((kb * 4) * 64 + lane) * 8];
            a0 = __builtin_amdgcn_mfma_f32_16x16x32_bf16(uu.s, wp[0 * 64], a0, 0, 0, 0);
            a1 = __builtin_amdgcn_mfma_f32_16x16x32_bf16(uu.s, wp[1 * 64], a1, 0, 0, 0);
            a2 = __builtin_amdgcn_mfma_f32_16x16x32_bf16(uu.s, wp[2 * 64], a2, 0, 0, 0);
            a3 = __builtin_amdgcn_mfma_f32_16x16x32_bf16(uu.s, wp[3 * 64], a3, 0, 0, 0);
        }
        // epilogue: D[q*4+r][ct*16+l16] -> bf16 rows via per-wave LDS scratch
        unsigned short* st = estage[wid];
        #pragma unroll
        for (int r = 0; r < 4; ++r) {
            int rr = (q * 4 + r) * 72 + l16;
            st[rr + 0 * 16] = f2bf(a0[r]);
            st[rr + 1 * 16] = f2bf(a1[r]);
            st[rr + 2 * 16] = f2bf(a2[r]);
            st[rr + 3 * 16] = f2bf(a3[r]);
        }
        #pragma unroll
        for (int i = 0; i < 4; ++i) {
            int row = i * 4 + q;
            uint2 v = *(const uint2*)&st[row * 72 + l16 * 4];
            *(uint2*)(h + (size_t)(t * 16 + row) * 64 + l16 * 4) = v;
        }
    }

    grid_bar(bar, NBLK);          // h complete, device-visible

    // =====================================================================
    // Phase 2: o1 = bf16( relu(A @ h) @ W2 )
    // =====================================================================
    for (int g = blockIdx.x; g < NG64; g += NBLK) {
        const int base = g * 64 + wid * 16;
        unsigned short* st = estage[wid];
        for (int i = 0; i < 4; ++i) {
            int row = base + i * 4 + q;
            int rc  = row < N_NODES ? row : N_NODES - 1;
            const int*   ci = colind + (size_t)rc * DEG;
            const float* vv = vals   + (size_t)rc * DEG;
            float s0 = 0.f, s1 = 0.f, s2 = 0.f, s3 = 0.f;
            #pragma unroll
            for (int e = 0; e < DEG; ++e) {
                int   c = ci[e];
                float v = vv[e];
                uint2 b = *(const uint2*)(h + (size_t)c * 64 + l16 * 4);
                s0 += v * bflo(b.x); s1 += v * bfhi(b.x);
                s2 += v * bflo(b.y); s3 += v * bfhi(b.y);
            }
            s0 = fmaxf(s0, 0.f); s1 = fmaxf(s1, 0.f);
            s2 = fmaxf(s2, 0.f); s3 = fmaxf(s3, 0.f);
            ushort4 p;
            p.x = f2bf(s0); p.y = f2bf(s1); p.z = f2bf(s2); p.w = f2bf(s3);
            *(ushort4*)&st[(i * 4 + q) * 72 + l16 * 4] = p;
        }
        // wave-private LDS: DS in-order per wave, no barrier needed
        f32x4 a0 = {0,0,0,0}, a1 = {0,0,0,0}, a2 = {0,0,0,0}, a3 = {0,0,0,0};
        #pragma unroll
        for (int kb = 0; kb < 2; ++kb) {
            short8 af = *(const short8*)&st[l16 * 72 + kb * 32 + q * 8];
            const short8* wp = (const short8*)&wfrag2[(size_t)((kb * 4) * 64 + lane) * 8];
            a0 = __builtin_amdgcn_mfma_f32_16x16x32_bf16(af, wp[0 * 64], a0, 0, 0, 0);
            a1 = __builtin_amdgcn_mfma_f32_16x16x32_bf16(af, wp[1 * 64], a1, 0, 0, 0);
            a2 = __builtin_amdgcn_mfma_f32_16x16x32_bf16(af, wp[2 * 64], a2, 0, 0, 0);
            a3 = __builtin_amdgcn_mfma_f32_16x16x32_bf16(af, wp[3 * 64], a3, 0, 0, 0);
        }
        #pragma unroll
        for (int r = 0; r < 4; ++r) {
            int rr = (q * 4 + r) * 72 + l16;
            st[rr + 0 * 16] = f2bf(a0[r]);
            st[rr + 1 * 16] = f2bf(a1[r]);
            st[rr + 2 * 16] = f2bf(a2[r]);
            st[rr + 3 * 16] = f2bf(a3[r]);
        }
        #pragma unroll
        for (int i = 0; i < 4; ++i) {
            int row = base + i * 4 + q;
            if (row < N_NODES) {
                uint2 v = *(const uint2*)&st[(i * 4 + q) * 72 + l16 * 4];
                *(uint2*)(o1 + (size_t)row * 64 + l16 * 4) = v;
            }
        }
    }

    grid_bar(bar, 2 * NBLK);      // o1 complete, device-visible

    // =====================================================================
    // Phase 3: out(fp32) = A @ o1
    // =====================================================================
    for (int t = blockIdx.x * 4 + wid; t < NT16; t += NBLK * 4) {
        #pragma unroll
        for (int i = 0; i < 4; ++i) {
            int row = t * 16 + i * 4 + q;
            const int*   ci = colind + (size_t)row * DEG;
            const float* vv = vals   + (size_t)row * DEG;
            float s0 = 0.f, s1 = 0.f, s2 = 0.f, s3 = 0.f;
            #pragma unroll
            for (int e = 0; e < DEG; ++e) {
                int   c = ci[e];
                float v = vv[e];
                uint2 b = *(const uint2*)(o1 + (size_t)c * 64 + l16 * 4);
                s0 += v * bflo(b.x); s1 += v * bfhi(b.x);
                s2 += v * bflo(b.y); s3 += v * bfhi(b.y);
            }
            float4 o; o.x = s0; o.y = s1; o.z = s2; o.w = s3;
            *(float4*)(out + (size_t)row * 64 + l16 * 4) = o;
        }
    }
}

extern "C" void kernel_launch(void* const* d_in, const int* in_sizes, int n_in,
                              void* d_out, int out_size, void* d_ws, size_t ws_size,
                              hipStream_t stream) {
    const float* X      = (const float*)d_in[0];   // [N,256]
    const float* W1     = (const float*)d_in[1];   // [256,64]
    const float* W2     = (const float*)d_in[2];   // [64,64]
    const float* vals   = (const float*)d_in[3];   // [NNZ]
    // d_in[4] = rowptr (fixed degree, unused)
    const int*   colind = (const int*)d_in[5];     // [NNZ]
    float*       out    = (float*)d_out;           // [N,64] fp32

    unsigned*       bar = (unsigned*)d_ws;                          // poisoned 0xAA each launch
    unsigned short* h   = (unsigned short*)((char*)d_ws + 256);     // [N,64] bf16
    unsigned short* o1  = h + (size_t)N_NODES * 64;                 // [N,64] bf16

    hipLaunchKernelGGL(gcn_fused, dim3(NBLK), dim3(256), 0, stream,
                       X, W1, W2, vals, colind, out, bar, h, o1);
}

// Round 5
// 271.362 us; speedup vs baseline: 1.9236x; 1.9236x over previous
//
#include <hip/hip_runtime.h>

#define N_NODES 100000
#define DEG 16
#define NT16 6250             // 16-row tiles (100000/16)
#define NG64 1563             // 64-row groups (ceil)
#define G1_BLOCKS 768         // 3 blocks/CU (41 KB LDS), all resident
#define G1_WSTRIDE (G1_BLOCKS * 4)

typedef __attribute__((ext_vector_type(8))) short short8;   // 8 bf16
typedef __attribute__((ext_vector_type(4))) float f32x4;

__device__ inline unsigned short f2bf(float f) {
    union { float f; unsigned u; } v; v.f = f;
    unsigned u = v.u;
    u += 0x7FFFu + ((u >> 16) & 1u);    // RNE
    return (unsigned short)(u >> 16);
}
__device__ inline unsigned pk2bf(float a, float b) {
    return (unsigned)f2bf(a) | ((unsigned)f2bf(b) << 16);
}
__device__ inline float bflo(unsigned u) {
    union { unsigned u; float f; } v; v.u = u << 16; return v.f;
}
__device__ inline float bfhi(unsigned u) {
    union { unsigned u; float f; } v; v.u = u & 0xFFFF0000u; return v.f;
}

// ---------------------------------------------------------------------------
// GEMM1: h[M,64](bf16) = X[M,256](fp32) @ W1[256,64](fp32).
// - W staged via 16 independent float4 loads/thread (one latency, not 64).
// - No A-stage LDS: coalesced X loads + ds_bpermute into A-fragment layout
//   (verified R4: lane t's frag comes from source lane ((t&15)<<2)|(t>>4)).
// - Whole next tile prefetched into registers during current tile's compute.
// LDS = 32 KB wfrag + 9 KB epilogue = 41 KB -> 3 blocks/CU.
// ---------------------------------------------------------------------------
__global__ __launch_bounds__(256, 3) void gemm1_k256(const float* __restrict__ X,
                                                     const float* __restrict__ W1,
                                                     unsigned short* __restrict__ h)
{
    __shared__ unsigned short wfrag[256 * 64];      // 32 KB, B-fragment order
    __shared__ unsigned short estage[4][16 * 72];   //  9 KB, per-wave epilogue

    const int tid  = threadIdx.x;
    const int lane = tid & 63;
    const int wid  = tid >> 6;
    const int q    = lane >> 4;
    const int l16  = lane & 15;

    // ---- W1 staging: thread tid owns W1 row k=tid (16 float4, all in flight) ----
    {
        float4 wr[16];
        #pragma unroll
        for (int i = 0; i < 16; ++i)
            wr[i] = *(const float4*)(W1 + tid * 64 + i * 4);
        const int kb  = tid >> 5;
        const int j   = tid & 7;
        const int lnr = ((tid >> 3) & 3) * 16;
        #pragma unroll
        for (int c = 0; c < 64; ++c) {
            float f = ((c & 3) == 0) ? wr[c >> 2].x :
                      ((c & 3) == 1) ? wr[c >> 2].y :
                      ((c & 3) == 2) ? wr[c >> 2].z : wr[c >> 2].w;
            wfrag[(((kb * 4) + (c >> 4)) * 64 + lnr + (c & 15)) * 8 + j] = f2bf(f);
        }
    }
    __syncthreads();

    const int bpidx = (((l16 << 2) | q) << 2);   // source lane * 4 for bpermute
    int t = blockIdx.x * 4 + wid;                 // < 3072 <= NT16: prologue valid

    float4 pf[16];
    {   // lane s loads X[t*16 + (s>>2)][(s&3)*8 + kb*32 .. +7]
        const float* xb = X + ((size_t)t * 16 + (lane >> 2)) * 256 + (lane & 3) * 8;
        #pragma unroll
        for (int kb = 0; kb < 8; ++kb) {
            pf[2 * kb]     = *(const float4*)(xb + kb * 32);
            pf[2 * kb + 1] = *(const float4*)(xb + kb * 32 + 4);
        }
    }

    while (t < NT16) {
        // convert whole tile to packed bf16 (frees pf for next prefetch)
        unsigned cv[32];
        #pragma unroll
        for (int i = 0; i < 16; ++i) {
            cv[2 * i]     = pk2bf(pf[i].x, pf[i].y);
            cv[2 * i + 1] = pk2bf(pf[i].z, pf[i].w);
        }
        const int tn = t + G1_WSTRIDE;
        if (tn < NT16) {
            const float* xb = X + ((size_t)tn * 16 + (lane >> 2)) * 256 + (lane & 3) * 8;
            #pragma unroll
            for (int kb = 0; kb < 8; ++kb) {
                pf[2 * kb]     = *(const float4*)(xb + kb * 32);
                pf[2 * kb + 1] = *(const float4*)(xb + kb * 32 + 4);
            }
        }

        f32x4 a0 = {0,0,0,0}, a1 = {0,0,0,0}, a2 = {0,0,0,0}, a3 = {0,0,0,0};
        #pragma unroll
        for (int kb = 0; kb < 8; ++kb) {
            union { int u[4]; short8 s; } uu;
            uu.u[0] = __builtin_amdgcn_ds_bpermute(bpidx, (int)cv[4 * kb + 0]);
            uu.u[1] = __builtin_amdgcn_ds_bpermute(bpidx, (int)cv[4 * kb + 1]);
            uu.u[2] = __builtin_amdgcn_ds_bpermute(bpidx, (int)cv[4 * kb + 2]);
            uu.u[3] = __builtin_amdgcn_ds_bpermute(bpidx, (int)cv[4 * kb + 3]);
            const short8* wp = (const short8*)&wfrag[(size_t)((kb * 4) * 64 + lane) * 8];
            a0 = __builtin_amdgcn_mfma_f32_16x16x32_bf16(uu.s, wp[0 * 64], a0, 0, 0, 0);
            a1 = __builtin_amdgcn_mfma_f32_16x16x32_bf16(uu.s, wp[1 * 64], a1, 0, 0, 0);
            a2 = __builtin_amdgcn_mfma_f32_16x16x32_bf16(uu.s, wp[2 * 64], a2, 0, 0, 0);
            a3 = __builtin_amdgcn_mfma_f32_16x16x32_bf16(uu.s, wp[3 * 64], a3, 0, 0, 0);
        }

        // epilogue: D[q*4+r][ct*16+l16] -> bf16 rows via per-wave LDS, uint2 stores
        unsigned short* st = estage[wid];
        #pragma unroll
        for (int r = 0; r < 4; ++r) {
            int rr = (q * 4 + r) * 72 + l16;
            st[rr + 0 * 16] = f2bf(a0[r]);
            st[rr + 1 * 16] = f2bf(a1[r]);
            st[rr + 2 * 16] = f2bf(a2[r]);
            st[rr + 3 * 16] = f2bf(a3[r]);
        }
        #pragma unroll
        for (int i = 0; i < 4; ++i) {
            int row = i * 4 + q;
            uint2 v = *(const uint2*)&st[row * 72 + l16 * 4];
            *(uint2*)(h + (size_t)(t * 16 + row) * 64 + l16 * 4) = v;
        }
        t = tn;
    }
}

// ---------------------------------------------------------------------------
// Row gather helper: acc += sum_e vals[e] * B[colind[e]][l16*4 .. +3]
// All 16 gathers independent (int4/float4 index loads, uint2 row reads).
// ---------------------------------------------------------------------------
__device__ inline void gather16(const unsigned short* __restrict__ B,
                                const int* __restrict__ ci, const float* __restrict__ vv,
                                int l16, float& a0, float& a1, float& a2, float& a3)
{
    int4 c0 = ((const int4*)ci)[0], c1 = ((const int4*)ci)[1],
         c2 = ((const int4*)ci)[2], c3 = ((const int4*)ci)[3];
    float4 v0 = ((const float4*)vv)[0], v1 = ((const float4*)vv)[1],
           v2 = ((const float4*)vv)[2], v3 = ((const float4*)vv)[3];
    const int off = l16 * 4;
    uint2 g0  = *(const uint2*)(B + (size_t)c0.x * 64 + off);
    uint2 g1  = *(const uint2*)(B + (size_t)c0.y * 64 + off);
    uint2 g2  = *(const uint2*)(B + (size_t)c0.z * 64 + off);
    uint2 g3  = *(const uint2*)(B + (size_t)c0.w * 64 + off);
    uint2 g4  = *(const uint2*)(B + (size_t)c1.x * 64 + off);
    uint2 g5  = *(const uint2*)(B + (size_t)c1.y * 64 + off);
    uint2 g6  = *(const uint2*)(B + (size_t)c1.z * 64 + off);
    uint2 g7  = *(const uint2*)(B + (size_t)c1.w * 64 + off);
    uint2 g8  = *(const uint2*)(B + (size_t)c2.x * 64 + off);
    uint2 g9  = *(const uint2*)(B + (size_t)c2.y * 64 + off);
    uint2 g10 = *(const uint2*)(B + (size_t)c2.z * 64 + off);
    uint2 g11 = *(const uint2*)(B + (size_t)c2.w * 64 + off);
    uint2 g12 = *(const uint2*)(B + (size_t)c3.x * 64 + off);
    uint2 g13 = *(const uint2*)(B + (size_t)c3.y * 64 + off);
    uint2 g14 = *(const uint2*)(B + (size_t)c3.z * 64 + off);
    uint2 g15 = *(const uint2*)(B + (size_t)c3.w * 64 + off);
#define ACC(g, s) \
    a0 += (s) * bflo((g).x); a1 += (s) * bfhi((g).x); \
    a2 += (s) * bflo((g).y); a3 += (s) * bfhi((g).y);
    ACC(g0,  v0.x) ACC(g1,  v0.y) ACC(g2,  v0.z) ACC(g3,  v0.w)
    ACC(g4,  v1.x) ACC(g5,  v1.y) ACC(g6,  v1.z) ACC(g7,  v1.w)
    ACC(g8,  v2.x) ACC(g9,  v2.y) ACC(g10, v2.z) ACC(g11, v2.w)
    ACC(g12, v3.x) ACC(g13, v3.y) ACC(g14, v3.z) ACC(g15, v3.w)
#undef ACC
}

// ---------------------------------------------------------------------------
// Fused SpMM1 + ReLU + GEMM2: o1 = bf16( relu(A @ h) @ W2 ).  17 KB LDS.
// ---------------------------------------------------------------------------
__global__ __launch_bounds__(256) void spmm_gemm2(const int* __restrict__ colind,
                                                  const float* __restrict__ vals,
                                                  const unsigned short* __restrict__ h,
                                                  const float* __restrict__ W2,
                                                  unsigned short* __restrict__ o1)
{
    __shared__ unsigned short wfrag2[64 * 64];      // 8 KB
    __shared__ unsigned short stage[4][16 * 72];    // 9 KB

    const int tid  = threadIdx.x;
    const int lane = tid & 63;
    const int wid  = tid >> 6;
    const int q    = lane >> 4;
    const int l16  = lane & 15;

    // ---- W2 staging: thread owns quarter-row (4 float4 loads) ----
    {
        const int r4 = tid >> 2;      // row 0..63
        const int qt = tid & 3;       // col quarter
        float4 wr[4];
        #pragma unroll
        for (int i = 0; i < 4; ++i)
            wr[i] = *(const float4*)(W2 + r4 * 64 + qt * 16 + i * 4);
        const int kb  = r4 >> 5;
        const int j   = r4 & 7;
        const int lnr = ((r4 >> 3) & 3) * 16;
        #pragma unroll
        for (int c = 0; c < 16; ++c) {
            float f = ((c & 3) == 0) ? wr[c >> 2].x :
                      ((c & 3) == 1) ? wr[c >> 2].y :
                      ((c & 3) == 2) ? wr[c >> 2].z : wr[c >> 2].w;
            wfrag2[(((kb * 4) + qt) * 64 + lnr + c) * 8 + j] = f2bf(f);
        }
    }
    __syncthreads();

    const int base = blockIdx.x * 64 + wid * 16;    // grid 1563 covers 100032
    unsigned short* st = stage[wid];

    for (int i = 0; i < 4; ++i) {
        int row = base + i * 4 + q;
        int rc  = row < N_NODES ? row : N_NODES - 1;
        float a0 = 0.f, a1 = 0.f, a2 = 0.f, a3 = 0.f;
        gather16(h, colind + (size_t)rc * DEG, vals + (size_t)rc * DEG, l16, a0, a1, a2, a3);
        a0 = fmaxf(a0, 0.f); a1 = fmaxf(a1, 0.f);
        a2 = fmaxf(a2, 0.f); a3 = fmaxf(a3, 0.f);
        ushort4 p;
        p.x = f2bf(a0); p.y = f2bf(a1); p.z = f2bf(a2); p.w = f2bf(a3);
        *(ushort4*)&st[(i * 4 + q) * 72 + l16 * 4] = p;
    }
    // wave-private LDS slice: DS ops in-order per wave, no barrier needed

    f32x4 a0 = {0,0,0,0}, a1 = {0,0,0,0}, a2 = {0,0,0,0}, a3 = {0,0,0,0};
    #pragma unroll
    for (int kb = 0; kb < 2; ++kb) {
        short8 af = *(const short8*)&st[l16 * 72 + kb * 32 + q * 8];
        const short8* wp = (const short8*)&wfrag2[(size_t)((kb * 4) * 64 + lane) * 8];
        a0 = __builtin_amdgcn_mfma_f32_16x16x32_bf16(af, wp[0 * 64], a0, 0, 0, 0);
        a1 = __builtin_amdgcn_mfma_f32_16x16x32_bf16(af, wp[1 * 64], a1, 0, 0, 0);
        a2 = __builtin_amdgcn_mfma_f32_16x16x32_bf16(af, wp[2 * 64], a2, 0, 0, 0);
        a3 = __builtin_amdgcn_mfma_f32_16x16x32_bf16(af, wp[3 * 64], a3, 0, 0, 0);
    }
    #pragma unroll
    for (int r = 0; r < 4; ++r) {
        int rr = (q * 4 + r) * 72 + l16;
        st[rr + 0 * 16] = f2bf(a0[r]);
        st[rr + 1 * 16] = f2bf(a1[r]);
        st[rr + 2 * 16] = f2bf(a2[r]);
        st[rr + 3 * 16] = f2bf(a3[r]);
    }
    #pragma unroll
    for (int i = 0; i < 4; ++i) {
        int row = base + i * 4 + q;
        if (row < N_NODES) {
            uint2 v = *(const uint2*)&st[(i * 4 + q) * 72 + l16 * 4];
            *(uint2*)(o1 + (size_t)row * 64 + l16 * 4) = v;
        }
    }
}

// ---------------------------------------------------------------------------
// SpMM2: out(fp32) = A @ o1(bf16). No LDS, max occupancy.
// ---------------------------------------------------------------------------
__global__ __launch_bounds__(256) void spmm_out(const int* __restrict__ colind,
                                                const float* __restrict__ vals,
                                                const unsigned short* __restrict__ B,
                                                float* __restrict__ out)
{
    const int tid  = threadIdx.x;
    const int lane = tid & 63;
    const int wid  = tid >> 6;
    const int q    = lane >> 4;
    const int l16  = lane & 15;
    const int row  = (blockIdx.x * 4 + wid) * 4 + q;   // grid 6250 covers N exactly

    float a0 = 0.f, a1 = 0.f, a2 = 0.f, a3 = 0.f;
    gather16(B, colind + (size_t)row * DEG, vals + (size_t)row * DEG, l16, a0, a1, a2, a3);
    float4 o; o.x = a0; o.y = a1; o.z = a2; o.w = a3;
    *(float4*)(out + (size_t)row * 64 + l16 * 4) = o;
}

extern "C" void kernel_launch(void* const* d_in, const int* in_sizes, int n_in,
                              void* d_out, int out_size, void* d_ws, size_t ws_size,
                              hipStream_t stream) {
    const float* X      = (const float*)d_in[0];   // [N,256]
    const float* W1     = (const float*)d_in[1];   // [256,64]
    const float* W2     = (const float*)d_in[2];   // [64,64]
    const float* vals   = (const float*)d_in[3];   // [NNZ]
    // d_in[4] = rowptr (fixed degree, unused)
    const int*   colind = (const int*)d_in[5];     // [NNZ]
    float*       out    = (float*)d_out;           // [N,64] fp32

    unsigned short* h  = (unsigned short*)d_ws;        // [N,64] bf16
    unsigned short* o1 = h + (size_t)N_NODES * 64;     // [N,64] bf16 (no alias)

    hipLaunchKernelGGL(gemm1_k256, dim3(G1_BLOCKS), dim3(256), 0, stream, X, W1, h);
    hipLaunchKernelGGL(spmm_gemm2, dim3(NG64), dim3(256), 0, stream,
                       colind, vals, h, W2, o1);
    hipLaunchKernelGGL(spmm_out, dim3(N_NODES / 16), dim3(256), 0, stream,
                       colind, vals, o1, out);
}

// Round 6
// 234.831 us; speedup vs baseline: 2.2229x; 1.1556x over previous
//
#include <hip/hip_runtime.h>

#define N_NODES 100000
#define DEG 16
#define NT16 6250             // 16-row tiles (100000/16)
#define NG64 1563             // 64-row groups (ceil)
#define G1_BLOCKS 768         // 3 blocks/CU (41 KB LDS)
#define G1_WSTRIDE (G1_BLOCKS * 4)

typedef __attribute__((ext_vector_type(8))) short short8;   // 8 bf16
typedef __attribute__((ext_vector_type(4))) float f32x4;

__device__ inline unsigned short f2bf(float f) {
    union { float f; unsigned u; } v; v.f = f;
    unsigned u = v.u;
    u += 0x7FFFu + ((u >> 16) & 1u);    // RNE
    return (unsigned short)(u >> 16);
}
__device__ inline unsigned pk2bf(float a, float b) {
    return (unsigned)f2bf(a) | ((unsigned)f2bf(b) << 16);
}
__device__ inline float bflo(unsigned u) {
    union { unsigned u; float f; } v; v.u = u << 16; return v.f;
}
__device__ inline float bfhi(unsigned u) {
    union { unsigned u; float f; } v; v.u = u & 0xFFFF0000u; return v.f;
}

// ---------------------------------------------------------------------------
// GEMM1: h[M,64](bf16) = X[M,256](fp32) @ W1[256,64](fp32).
// Half-tile software pipeline, spill-free by construction:
//   pa[8]/pb[8] (32 VGPR each) hold half a 16x256 tile; while one half
//   computes (bpermute -> MFMA), the other half's 8 KB of loads is in flight.
// Lane mapping (verified R4/R5): lane s loads X[t*16+(s>>2)][(s&3)*8 + kb*32 ..+7];
// A-frag for lane t comes from source lane ((t&15)<<2)|(t>>4) via ds_bpermute.
// LDS = 32 KB wfrag + 9 KB epilogue = 41 KB -> 3 blocks/CU (12 waves).
// ---------------------------------------------------------------------------
__global__ __launch_bounds__(256) void gemm1_k256(const float* __restrict__ X,
                                                  const float* __restrict__ W1,
                                                  unsigned short* __restrict__ h)
{
    __shared__ unsigned short wfrag[256 * 64];      // 32 KB, B-fragment order
    __shared__ unsigned short estage[4][16 * 72];   //  9 KB, per-wave epilogue

    const int tid  = threadIdx.x;
    const int lane = tid & 63;
    const int wid  = tid >> 6;
    const int q    = lane >> 4;
    const int l16  = lane & 15;

    // ---- W1 staging: thread tid owns W1 row k=tid (16 independent float4) ----
    {
        float4 wr[16];
        #pragma unroll
        for (int i = 0; i < 16; ++i)
            wr[i] = *(const float4*)(W1 + tid * 64 + i * 4);
        const int kb  = tid >> 5;
        const int j   = tid & 7;
        const int lnr = ((tid >> 3) & 3) * 16;
        #pragma unroll
        for (int c = 0; c < 64; ++c) {
            float f = ((c & 3) == 0) ? wr[c >> 2].x :
                      ((c & 3) == 1) ? wr[c >> 2].y :
                      ((c & 3) == 2) ? wr[c >> 2].z : wr[c >> 2].w;
            wfrag[(((kb * 4) + (c >> 4)) * 64 + lnr + (c & 15)) * 8 + j] = f2bf(f);
        }
    }
    __syncthreads();

    const int bpidx = (((l16 << 2) | q) << 2);   // source lane * 4 for bpermute
    const size_t xoff = (size_t)(lane >> 2) * 256 + (lane & 3) * 8;

    int t = blockIdx.x * 4 + wid;                 // < 3072 <= NT16: prologue valid

    float4 pa[8];                                 // half0: kb = 0..3
    {
        const float* xb = X + (size_t)t * 16 * 256 + xoff;
        #pragma unroll
        for (int kb = 0; kb < 4; ++kb) {
            pa[2 * kb]     = *(const float4*)(xb + kb * 32);
            pa[2 * kb + 1] = *(const float4*)(xb + kb * 32 + 4);
        }
    }

    while (t < NT16) {
        const float* xb = X + (size_t)t * 16 * 256 + xoff;
        // issue half1 loads (in flight during half0 compute)
        float4 pb[8];
        #pragma unroll
        for (int kb = 4; kb < 8; ++kb) {
            pb[2 * (kb - 4)]     = *(const float4*)(xb + kb * 32);
            pb[2 * (kb - 4) + 1] = *(const float4*)(xb + kb * 32 + 4);
        }

        f32x4 a0 = {0,0,0,0}, a1 = {0,0,0,0}, a2 = {0,0,0,0}, a3 = {0,0,0,0};

        // compute half0 (waits vmcnt for pa only)
        #pragma unroll
        for (int kb = 0; kb < 4; ++kb) {
            union { int u[4]; short8 s; } uu;
            uu.u[0] = __builtin_amdgcn_ds_bpermute(bpidx, (int)pk2bf(pa[2*kb].x,   pa[2*kb].y));
            uu.u[1] = __builtin_amdgcn_ds_bpermute(bpidx, (int)pk2bf(pa[2*kb].z,   pa[2*kb].w));
            uu.u[2] = __builtin_amdgcn_ds_bpermute(bpidx, (int)pk2bf(pa[2*kb+1].x, pa[2*kb+1].y));
            uu.u[3] = __builtin_amdgcn_ds_bpermute(bpidx, (int)pk2bf(pa[2*kb+1].z, pa[2*kb+1].w));
            const short8* wp = (const short8*)&wfrag[(size_t)((kb * 4) * 64 + lane) * 8];
            a0 = __builtin_amdgcn_mfma_f32_16x16x32_bf16(uu.s, wp[0 * 64], a0, 0, 0, 0);
            a1 = __builtin_amdgcn_mfma_f32_16x16x32_bf16(uu.s, wp[1 * 64], a1, 0, 0, 0);
            a2 = __builtin_amdgcn_mfma_f32_16x16x32_bf16(uu.s, wp[2 * 64], a2, 0, 0, 0);
            a3 = __builtin_amdgcn_mfma_f32_16x16x32_bf16(uu.s, wp[3 * 64], a3, 0, 0, 0);
        }

        // issue next tile's half0 loads (in flight during half1 compute + epilogue)
        const int tn = t + G1_WSTRIDE;
        if (tn < NT16) {
            const float* xn = X + (size_t)tn * 16 * 256 + xoff;
            #pragma unroll
            for (int kb = 0; kb < 4; ++kb) {
                pa[2 * kb]     = *(const float4*)(xn + kb * 32);
                pa[2 * kb + 1] = *(const float4*)(xn + kb * 32 + 4);
            }
        }

        // compute half1 (waits vmcnt for pb only)
        #pragma unroll
        for (int kb = 4; kb < 8; ++kb) {
            const int i = kb - 4;
            union { int u[4]; short8 s; } uu;
            uu.u[0] = __builtin_amdgcn_ds_bpermute(bpidx, (int)pk2bf(pb[2*i].x,   pb[2*i].y));
            uu.u[1] = __builtin_amdgcn_ds_bpermute(bpidx, (int)pk2bf(pb[2*i].z,   pb[2*i].w));
            uu.u[2] = __builtin_amdgcn_ds_bpermute(bpidx, (int)pk2bf(pb[2*i+1].x, pb[2*i+1].y));
            uu.u[3] = __builtin_amdgcn_ds_bpermute(bpidx, (int)pk2bf(pb[2*i+1].z, pb[2*i+1].w));
            const short8* wp = (const short8*)&wfrag[(size_t)((kb * 4) * 64 + lane) * 8];
            a0 = __builtin_amdgcn_mfma_f32_16x16x32_bf16(uu.s, wp[0 * 64], a0, 0, 0, 0);
            a1 = __builtin_amdgcn_mfma_f32_16x16x32_bf16(uu.s, wp[1 * 64], a1, 0, 0, 0);
            a2 = __builtin_amdgcn_mfma_f32_16x16x32_bf16(uu.s, wp[2 * 64], a2, 0, 0, 0);
            a3 = __builtin_amdgcn_mfma_f32_16x16x32_bf16(uu.s, wp[3 * 64], a3, 0, 0, 0);
        }

        // epilogue: D[q*4+r][ct*16+l16] -> bf16 rows via per-wave LDS, uint2 stores
        unsigned short* st = estage[wid];
        #pragma unroll
        for (int r = 0; r < 4; ++r) {
            int rr = (q * 4 + r) * 72 + l16;
            st[rr + 0 * 16] = f2bf(a0[r]);
            st[rr + 1 * 16] = f2bf(a1[r]);
            st[rr + 2 * 16] = f2bf(a2[r]);
            st[rr + 3 * 16] = f2bf(a3[r]);
        }
        #pragma unroll
        for (int i = 0; i < 4; ++i) {
            int row = i * 4 + q;
            uint2 v = *(const uint2*)&st[row * 72 + l16 * 4];
            *(uint2*)(h + (size_t)(t * 16 + row) * 64 + l16 * 4) = v;
        }
        t = tn;
    }
}

// ---------------------------------------------------------------------------
// Row gather helper: acc += sum_e vals[e] * B[colind[e]][l16*4 .. +3]
// All 16 gathers independent (int4/float4 index loads, uint2 row reads).
// ---------------------------------------------------------------------------
__device__ inline void gather16(const unsigned short* __restrict__ B,
                                const int* __restrict__ ci, const float* __restrict__ vv,
                                int l16, float& a0, float& a1, float& a2, float& a3)
{
    int4 c0 = ((const int4*)ci)[0], c1 = ((const int4*)ci)[1],
         c2 = ((const int4*)ci)[2], c3 = ((const int4*)ci)[3];
    float4 v0 = ((const float4*)vv)[0], v1 = ((const float4*)vv)[1],
           v2 = ((const float4*)vv)[2], v3 = ((const float4*)vv)[3];
    const int off = l16 * 4;
    uint2 g0  = *(const uint2*)(B + (size_t)c0.x * 64 + off);
    uint2 g1  = *(const uint2*)(B + (size_t)c0.y * 64 + off);
    uint2 g2  = *(const uint2*)(B + (size_t)c0.z * 64 + off);
    uint2 g3  = *(const uint2*)(B + (size_t)c0.w * 64 + off);
    uint2 g4  = *(const uint2*)(B + (size_t)c1.x * 64 + off);
    uint2 g5  = *(const uint2*)(B + (size_t)c1.y * 64 + off);
    uint2 g6  = *(const uint2*)(B + (size_t)c1.z * 64 + off);
    uint2 g7  = *(const uint2*)(B + (size_t)c1.w * 64 + off);
    uint2 g8  = *(const uint2*)(B + (size_t)c2.x * 64 + off);
    uint2 g9  = *(const uint2*)(B + (size_t)c2.y * 64 + off);
    uint2 g10 = *(const uint2*)(B + (size_t)c2.z * 64 + off);
    uint2 g11 = *(const uint2*)(B + (size_t)c2.w * 64 + off);
    uint2 g12 = *(const uint2*)(B + (size_t)c3.x * 64 + off);
    uint2 g13 = *(const uint2*)(B + (size_t)c3.y * 64 + off);
    uint2 g14 = *(const uint2*)(B + (size_t)c3.z * 64 + off);
    uint2 g15 = *(const uint2*)(B + (size_t)c3.w * 64 + off);
#define ACC(g, s) \
    a0 += (s) * bflo((g).x); a1 += (s) * bfhi((g).x); \
    a2 += (s) * bflo((g).y); a3 += (s) * bfhi((g).y);
    ACC(g0,  v0.x) ACC(g1,  v0.y) ACC(g2,  v0.z) ACC(g3,  v0.w)
    ACC(g4,  v1.x) ACC(g5,  v1.y) ACC(g6,  v1.z) ACC(g7,  v1.w)
    ACC(g8,  v2.x) ACC(g9,  v2.y) ACC(g10, v2.z) ACC(g11, v2.w)
    ACC(g12, v3.x) ACC(g13, v3.y) ACC(g14, v3.z) ACC(g15, v3.w)
#undef ACC
}

// ---------------------------------------------------------------------------
// Fused SpMM1 + ReLU + GEMM2: o1 = bf16( relu(A @ h) @ W2 ).  17 KB LDS.
// ---------------------------------------------------------------------------
__global__ __launch_bounds__(256) void spmm_gemm2(const int* __restrict__ colind,
                                                  const float* __restrict__ vals,
                                                  const unsigned short* __restrict__ h,
                                                  const float* __restrict__ W2,
                                                  unsigned short* __restrict__ o1)
{
    __shared__ unsigned short wfrag2[64 * 64];      // 8 KB
    __shared__ unsigned short stage[4][16 * 72];    // 9 KB

    const int tid  = threadIdx.x;
    const int lane = tid & 63;
    const int wid  = tid >> 6;
    const int q    = lane >> 4;
    const int l16  = lane & 15;

    // ---- W2 staging: thread owns quarter-row (4 independent float4) ----
    {
        const int r4 = tid >> 2;      // row 0..63
        const int qt = tid & 3;       // col quarter
        float4 wr[4];
        #pragma unroll
        for (int i = 0; i < 4; ++i)
            wr[i] = *(const float4*)(W2 + r4 * 64 + qt * 16 + i * 4);
        const int kb  = r4 >> 5;
        const int j   = r4 & 7;
        const int lnr = ((r4 >> 3) & 3) * 16;
        #pragma unroll
        for (int c = 0; c < 16; ++c) {
            float f = ((c & 3) == 0) ? wr[c >> 2].x :
                      ((c & 3) == 1) ? wr[c >> 2].y :
                      ((c & 3) == 2) ? wr[c >> 2].z : wr[c >> 2].w;
            wfrag2[(((kb * 4) + qt) * 64 + lnr + c) * 8 + j] = f2bf(f);
        }
    }
    __syncthreads();

    const int base = blockIdx.x * 64 + wid * 16;    // grid 1563 covers 100032
    unsigned short* st = stage[wid];

    for (int i = 0; i < 4; ++i) {
        int row = base + i * 4 + q;
        int rc  = row < N_NODES ? row : N_NODES - 1;
        float a0 = 0.f, a1 = 0.f, a2 = 0.f, a3 = 0.f;
        gather16(h, colind + (size_t)rc * DEG, vals + (size_t)rc * DEG, l16, a0, a1, a2, a3);
        a0 = fmaxf(a0, 0.f); a1 = fmaxf(a1, 0.f);
        a2 = fmaxf(a2, 0.f); a3 = fmaxf(a3, 0.f);
        ushort4 p;
        p.x = f2bf(a0); p.y = f2bf(a1); p.z = f2bf(a2); p.w = f2bf(a3);
        *(ushort4*)&st[(i * 4 + q) * 72 + l16 * 4] = p;
    }
    // wave-private LDS slice: DS ops in-order per wave, no barrier needed

    f32x4 a0 = {0,0,0,0}, a1 = {0,0,0,0}, a2 = {0,0,0,0}, a3 = {0,0,0,0};
    #pragma unroll
    for (int kb = 0; kb < 2; ++kb) {
        short8 af = *(const short8*)&st[l16 * 72 + kb * 32 + q * 8];
        const short8* wp = (const short8*)&wfrag2[(size_t)((kb * 4) * 64 + lane) * 8];
        a0 = __builtin_amdgcn_mfma_f32_16x16x32_bf16(af, wp[0 * 64], a0, 0, 0, 0);
        a1 = __builtin_amdgcn_mfma_f32_16x16x32_bf16(af, wp[1 * 64], a1, 0, 0, 0);
        a2 = __builtin_amdgcn_mfma_f32_16x16x32_bf16(af, wp[2 * 64], a2, 0, 0, 0);
        a3 = __builtin_amdgcn_mfma_f32_16x16x32_bf16(af, wp[3 * 64], a3, 0, 0, 0);
    }
    #pragma unroll
    for (int r = 0; r < 4; ++r) {
        int rr = (q * 4 + r) * 72 + l16;
        st[rr + 0 * 16] = f2bf(a0[r]);
        st[rr + 1 * 16] = f2bf(a1[r]);
        st[rr + 2 * 16] = f2bf(a2[r]);
        st[rr + 3 * 16] = f2bf(a3[r]);
    }
    #pragma unroll
    for (int i = 0; i < 4; ++i) {
        int row = base + i * 4 + q;
        if (row < N_NODES) {
            uint2 v = *(const uint2*)&st[(i * 4 + q) * 72 + l16 * 4];
            *(uint2*)(o1 + (size_t)row * 64 + l16 * 4) = v;
        }
    }
}

// ---------------------------------------------------------------------------
// SpMM2: out(fp32) = A @ o1(bf16). No LDS, max occupancy.
// ---------------------------------------------------------------------------
__global__ __launch_bounds__(256) void spmm_out(const int* __restrict__ colind,
                                                const float* __restrict__ vals,
                                                const unsigned short* __restrict__ B,
                                                float* __restrict__ out)
{
    const int tid  = threadIdx.x;
    const int lane = tid & 63;
    const int wid  = tid >> 6;
    const int q    = lane >> 4;
    const int l16  = lane & 15;
    const int row  = (blockIdx.x * 4 + wid) * 4 + q;   // grid 6250 covers N exactly

    float a0 = 0.f, a1 = 0.f, a2 = 0.f, a3 = 0.f;
    gather16(B, colind + (size_t)row * DEG, vals + (size_t)row * DEG, l16, a0, a1, a2, a3);
    float4 o; o.x = a0; o.y = a1; o.z = a2; o.w = a3;
    *(float4*)(out + (size_t)row * 64 + l16 * 4) = o;
}

extern "C" void kernel_launch(void* const* d_in, const int* in_sizes, int n_in,
                              void* d_out, int out_size, void* d_ws, size_t ws_size,
                              hipStream_t stream) {
    const float* X      = (const float*)d_in[0];   // [N,256]
    const float* W1     = (const float*)d_in[1];   // [256,64]
    const float* W2     = (const float*)d_in[2];   // [64,64]
    const float* vals   = (const float*)d_in[3];   // [NNZ]
    // d_in[4] = rowptr (fixed degree, unused)
    const int*   colind = (const int*)d_in[5];     // [NNZ]
    float*       out    = (float*)d_out;           // [N,64] fp32

    unsigned short* h  = (unsigned short*)d_ws;        // [N,64] bf16
    unsigned short* o1 = h + (size_t)N_NODES * 64;     // [N,64] bf16 (no alias)

    hipLaunchKernelGGL(gemm1_k256, dim3(G1_BLOCKS), dim3(256), 0, stream, X, W1, h);
    hipLaunchKernelGGL(spmm_gemm2, dim3(NG64), dim3(256), 0, stream,
                       colind, vals, h, W2, o1);
    hipLaunchKernelGGL(spmm_out, dim3(N_NODES / 16), dim3(256), 0, stream,
                       colind, vals, o1, out);
}

// Round 7
// 230.540 us; speedup vs baseline: 2.2642x; 1.0186x over previous
//
#include <hip/hip_runtime.h>

#define N_NODES 100000
#define DEG 16
#define NT16 6250             // 16-row tiles (100000/16)
#define NG64 1563             // 64-row groups (ceil)
#define G1_BLOCKS 782         // 3128 waves -> exactly <=2 tiles/wave
#define G1_WSTRIDE (G1_BLOCKS * 4)

typedef __attribute__((ext_vector_type(8))) short short8;   // 8 bf16
typedef __attribute__((ext_vector_type(4))) float f32x4;

__device__ inline unsigned short f2bf(float f) {
    union { float f; unsigned u; } v; v.f = f;
    unsigned u = v.u;
    u += 0x7FFFu + ((u >> 16) & 1u);    // RNE
    return (unsigned short)(u >> 16);
}
__device__ inline unsigned pk2bf(float a, float b) {
    return (unsigned)f2bf(a) | ((unsigned)f2bf(b) << 16);
}
__device__ inline float bflo(unsigned u) {
    union { unsigned u; float f; } v; v.u = u << 16; return v.f;
}
__device__ inline float bfhi(unsigned u) {
    union { unsigned u; float f; } v; v.u = u & 0xFFFF0000u; return v.f;
}

// ---------------------------------------------------------------------------
// GEMM1: h[M,64](bf16) = X[M,256](fp32) @ W1[256,64](fp32).
// Half-tile software pipeline (spill-free, verified R6); balanced 2 tiles/wave.
// W staging: thread owns 4 consecutive W-rows x 16 cols -> 16x ds_write_b64.
// LDS = 32 KB wfrag + 9 KB epilogue = 41 KB -> 3 blocks/CU.
// ---------------------------------------------------------------------------
__global__ __launch_bounds__(256) void gemm1_k256(const float* __restrict__ X,
                                                  const float* __restrict__ W1,
                                                  unsigned short* __restrict__ h)
{
    __shared__ unsigned short wfrag[256 * 64];      // 32 KB, B-fragment order
    __shared__ unsigned short estage[4][16 * 72];   //  9 KB, per-wave epilogue

    const int tid  = threadIdx.x;
    const int lane = tid & 63;
    const int wid  = tid >> 6;
    const int q    = lane >> 4;
    const int l16  = lane & 15;

    // ---- W1 staging: rows kg*4..+3, cols cq*16..+15 per thread ----
    // wfrag[((kb*4+ct)*64+ln)*8+j] = W1[kb*32+(ln>>4)*8+j][ct*16+(ln&15)]
    {
        const int kg = tid >> 2;          // 0..63
        const int cq = tid & 3;           // col quarter
        float4 wr[16];                    // [r][i]: W1[(kg*4+r)*64 + cq*16 + i*4]
        #pragma unroll
        for (int r = 0; r < 4; ++r)
            #pragma unroll
            for (int i = 0; i < 4; ++i)
                wr[r * 4 + i] = *(const float4*)(W1 + (kg * 4 + r) * 64 + cq * 16 + i * 4);
        const int kb  = kg >> 3;
        const int lnr = (((kg * 4) >> 3) & 3) * 16;
        const int jb  = (kg * 4) & 7;     // 0 or 4; j = jb + r contiguous
        #pragma unroll
        for (int c = 0; c < 16; ++c) {
            ushort4 w4;
            #pragma unroll
            for (int r = 0; r < 4; ++r) {
                float4 v = wr[r * 4 + (c >> 2)];
                float  f = ((c & 3) == 0) ? v.x : ((c & 3) == 1) ? v.y :
                           ((c & 3) == 2) ? v.z : v.w;
                ((unsigned short*)&w4)[r] = f2bf(f);
            }
            *(ushort4*)&wfrag[(((kb * 4) + cq) * 64 + lnr + c) * 8 + jb] = w4;
        }
    }
    __syncthreads();

    const int bpidx = (((l16 << 2) | q) << 2);   // source lane * 4 for bpermute
    const size_t xoff = (size_t)(lane >> 2) * 256 + (lane & 3) * 8;

    int t = blockIdx.x * 4 + wid;                 // < 3128 <= NT16

    float4 pa[8];                                 // half0: kb = 0..3
    {
        const float* xb = X + (size_t)t * 16 * 256 + xoff;
        #pragma unroll
        for (int kb = 0; kb < 4; ++kb) {
            pa[2 * kb]     = *(const float4*)(xb + kb * 32);
            pa[2 * kb + 1] = *(const float4*)(xb + kb * 32 + 4);
        }
    }

    while (t < NT16) {
        const float* xb = X + (size_t)t * 16 * 256 + xoff;
        float4 pb[8];                             // half1 loads in flight
        #pragma unroll
        for (int kb = 4; kb < 8; ++kb) {
            pb[2 * (kb - 4)]     = *(const float4*)(xb + kb * 32);
            pb[2 * (kb - 4) + 1] = *(const float4*)(xb + kb * 32 + 4);
        }

        f32x4 a0 = {0,0,0,0}, a1 = {0,0,0,0}, a2 = {0,0,0,0}, a3 = {0,0,0,0};

        #pragma unroll
        for (int kb = 0; kb < 4; ++kb) {          // compute half0
            union { int u[4]; short8 s; } uu;
            uu.u[0] = __builtin_amdgcn_ds_bpermute(bpidx, (int)pk2bf(pa[2*kb].x,   pa[2*kb].y));
            uu.u[1] = __builtin_amdgcn_ds_bpermute(bpidx, (int)pk2bf(pa[2*kb].z,   pa[2*kb].w));
            uu.u[2] = __builtin_amdgcn_ds_bpermute(bpidx, (int)pk2bf(pa[2*kb+1].x, pa[2*kb+1].y));
            uu.u[3] = __builtin_amdgcn_ds_bpermute(bpidx, (int)pk2bf(pa[2*kb+1].z, pa[2*kb+1].w));
            const short8* wp = (const short8*)&wfrag[(size_t)((kb * 4) * 64 + lane) * 8];
            a0 = __builtin_amdgcn_mfma_f32_16x16x32_bf16(uu.s, wp[0 * 64], a0, 0, 0, 0);
            a1 = __builtin_amdgcn_mfma_f32_16x16x32_bf16(uu.s, wp[1 * 64], a1, 0, 0, 0);
            a2 = __builtin_amdgcn_mfma_f32_16x16x32_bf16(uu.s, wp[2 * 64], a2, 0, 0, 0);
            a3 = __builtin_amdgcn_mfma_f32_16x16x32_bf16(uu.s, wp[3 * 64], a3, 0, 0, 0);
        }

        const int tn = t + G1_WSTRIDE;            // next tile's half0 in flight
        if (tn < NT16) {
            const float* xn = X + (size_t)tn * 16 * 256 + xoff;
            #pragma unroll
            for (int kb = 0; kb < 4; ++kb) {
                pa[2 * kb]     = *(const float4*)(xn + kb * 32);
                pa[2 * kb + 1] = *(const float4*)(xn + kb * 32 + 4);
            }
        }

        #pragma unroll
        for (int kb = 4; kb < 8; ++kb) {          // compute half1
            const int i = kb - 4;
            union { int u[4]; short8 s; } uu;
            uu.u[0] = __builtin_amdgcn_ds_bpermute(bpidx, (int)pk2bf(pb[2*i].x,   pb[2*i].y));
            uu.u[1] = __builtin_amdgcn_ds_bpermute(bpidx, (int)pk2bf(pb[2*i].z,   pb[2*i].w));
            uu.u[2] = __builtin_amdgcn_ds_bpermute(bpidx, (int)pk2bf(pb[2*i+1].x, pb[2*i+1].y));
            uu.u[3] = __builtin_amdgcn_ds_bpermute(bpidx, (int)pk2bf(pb[2*i+1].z, pb[2*i+1].w));
            const short8* wp = (const short8*)&wfrag[(size_t)((kb * 4) * 64 + lane) * 8];
            a0 = __builtin_amdgcn_mfma_f32_16x16x32_bf16(uu.s, wp[0 * 64], a0, 0, 0, 0);
            a1 = __builtin_amdgcn_mfma_f32_16x16x32_bf16(uu.s, wp[1 * 64], a1, 0, 0, 0);
            a2 = __builtin_amdgcn_mfma_f32_16x16x32_bf16(uu.s, wp[2 * 64], a2, 0, 0, 0);
            a3 = __builtin_amdgcn_mfma_f32_16x16x32_bf16(uu.s, wp[3 * 64], a3, 0, 0, 0);
        }

        // epilogue: D[q*4+r][ct*16+l16] -> bf16 rows via per-wave LDS
        unsigned short* st = estage[wid];
        #pragma unroll
        for (int r = 0; r < 4; ++r) {
            int rr = (q * 4 + r) * 72 + l16;
            st[rr + 0 * 16] = f2bf(a0[r]);
            st[rr + 1 * 16] = f2bf(a1[r]);
            st[rr + 2 * 16] = f2bf(a2[r]);
            st[rr + 3 * 16] = f2bf(a3[r]);
        }
        #pragma unroll
        for (int i = 0; i < 4; ++i) {
            int row = i * 4 + q;
            uint2 v = *(const uint2*)&st[row * 72 + l16 * 4];
            *(uint2*)(h + (size_t)(t * 16 + row) * 64 + l16 * 4) = v;
        }
        t = tn;
    }
}

// ---------------------------------------------------------------------------
// Row gather, 8 lanes/row x uint4: lane octet j8 covers cols j8*8..+7.
// One gather instruction serves 8 rows (vs 4 with uint2) -> half the vmem ops.
// 16 edges in 2 batches of 8 (keeps VGPR pressure ~70).
// ---------------------------------------------------------------------------
__device__ inline void gather_row8(const unsigned short* __restrict__ B,
                                   const int* __restrict__ ci,
                                   const float* __restrict__ vv,
                                   int j8, float* __restrict__ acc)
{
    #pragma unroll
    for (int b = 0; b < 2; ++b) {
        int4   c0 = ((const int4*)ci)[2 * b],   c1 = ((const int4*)ci)[2 * b + 1];
        float4 v0 = ((const float4*)vv)[2 * b], v1 = ((const float4*)vv)[2 * b + 1];
        uint4 g0 = *(const uint4*)(B + (size_t)c0.x * 64 + j8 * 8);
        uint4 g1 = *(const uint4*)(B + (size_t)c0.y * 64 + j8 * 8);
        uint4 g2 = *(const uint4*)(B + (size_t)c0.z * 64 + j8 * 8);
        uint4 g3 = *(const uint4*)(B + (size_t)c0.w * 64 + j8 * 8);
        uint4 g4 = *(const uint4*)(B + (size_t)c1.x * 64 + j8 * 8);
        uint4 g5 = *(const uint4*)(B + (size_t)c1.y * 64 + j8 * 8);
        uint4 g6 = *(const uint4*)(B + (size_t)c1.z * 64 + j8 * 8);
        uint4 g7 = *(const uint4*)(B + (size_t)c1.w * 64 + j8 * 8);
#define ACC8(g, s) \
        acc[0] += (s) * bflo((g).x); acc[1] += (s) * bfhi((g).x); \
        acc[2] += (s) * bflo((g).y); acc[3] += (s) * bfhi((g).y); \
        acc[4] += (s) * bflo((g).z); acc[5] += (s) * bfhi((g).z); \
        acc[6] += (s) * bflo((g).w); acc[7] += (s) * bfhi((g).w);
        ACC8(g0, v0.x) ACC8(g1, v0.y) ACC8(g2, v0.z) ACC8(g3, v0.w)
        ACC8(g4, v1.x) ACC8(g5, v1.y) ACC8(g6, v1.z) ACC8(g7, v1.w)
#undef ACC8
    }
}

// ---------------------------------------------------------------------------
// Fused SpMM1 + ReLU + GEMM2: o1 = bf16( relu(A @ h) @ W2 ).  17 KB LDS.
// Gathers 16 rows/wave in 2 passes of 8 (8 lanes/row x uint4).
// ---------------------------------------------------------------------------
__global__ __launch_bounds__(256) void spmm_gemm2(const int* __restrict__ colind,
                                                  const float* __restrict__ vals,
                                                  const unsigned short* __restrict__ h,
                                                  const float* __restrict__ W2,
                                                  unsigned short* __restrict__ o1)
{
    __shared__ unsigned short wfrag2[64 * 64];      // 8 KB
    __shared__ unsigned short stage[4][16 * 72];    // 9 KB

    const int tid  = threadIdx.x;
    const int lane = tid & 63;
    const int wid  = tid >> 6;
    const int q    = lane >> 4;
    const int l16  = lane & 15;

    // ---- W2 staging (rows r4, quarter qt) ----
    {
        const int r4 = tid >> 2;
        const int qt = tid & 3;
        float4 wr[4];
        #pragma unroll
        for (int i = 0; i < 4; ++i)
            wr[i] = *(const float4*)(W2 + r4 * 64 + qt * 16 + i * 4);
        const int kb  = r4 >> 5;
        const int j   = r4 & 7;
        const int lnr = ((r4 >> 3) & 3) * 16;
        #pragma unroll
        for (int c = 0; c < 16; ++c) {
            float f = ((c & 3) == 0) ? wr[c >> 2].x :
                      ((c & 3) == 1) ? wr[c >> 2].y :
                      ((c & 3) == 2) ? wr[c >> 2].z : wr[c >> 2].w;
            wfrag2[(((kb * 4) + qt) * 64 + lnr + c) * 8 + j] = f2bf(f);
        }
    }
    __syncthreads();

    const int base = blockIdx.x * 64 + wid * 16;    // grid 1563 covers 100032
    unsigned short* st = stage[wid];
    const int rl = lane >> 3;       // local row within pass
    const int j8 = lane & 7;        // col octet

    #pragma unroll
    for (int p = 0; p < 2; ++p) {
        int lr  = p * 8 + rl;       // local row 0..15
        int row = base + lr;
        int rc  = row < N_NODES ? row : N_NODES - 1;
        float acc[8] = {0.f,0.f,0.f,0.f,0.f,0.f,0.f,0.f};
        gather_row8(h, colind + (size_t)rc * DEG, vals + (size_t)rc * DEG, j8, acc);
        uint4 pk;
        pk.x = pk2bf(fmaxf(acc[0], 0.f), fmaxf(acc[1], 0.f));
        pk.y = pk2bf(fmaxf(acc[2], 0.f), fmaxf(acc[3], 0.f));
        pk.z = pk2bf(fmaxf(acc[4], 0.f), fmaxf(acc[5], 0.f));
        pk.w = pk2bf(fmaxf(acc[6], 0.f), fmaxf(acc[7], 0.f));
        *(uint4*)&st[lr * 72 + j8 * 8] = pk;       // 144B row stride: 16B aligned
    }
    // wave-private LDS slice: DS ops in-order per wave, no barrier needed

    f32x4 a0 = {0,0,0,0}, a1 = {0,0,0,0}, a2 = {0,0,0,0}, a3 = {0,0,0,0};
    #pragma unroll
    for (int kb = 0; kb < 2; ++kb) {
        short8 af = *(const short8*)&st[l16 * 72 + kb * 32 + q * 8];
        const short8* wp = (const short8*)&wfrag2[(size_t)((kb * 4) * 64 + lane) * 8];
        a0 = __builtin_amdgcn_mfma_f32_16x16x32_bf16(af, wp[0 * 64], a0, 0, 0, 0);
        a1 = __builtin_amdgcn_mfma_f32_16x16x32_bf16(af, wp[1 * 64], a1, 0, 0, 0);
        a2 = __builtin_amdgcn_mfma_f32_16x16x32_bf16(af, wp[2 * 64], a2, 0, 0, 0);
        a3 = __builtin_amdgcn_mfma_f32_16x16x32_bf16(af, wp[3 * 64], a3, 0, 0, 0);
    }
    #pragma unroll
    for (int r = 0; r < 4; ++r) {
        int rr = (q * 4 + r) * 72 + l16;
        st[rr + 0 * 16] = f2bf(a0[r]);
        st[rr + 1 * 16] = f2bf(a1[r]);
        st[rr + 2 * 16] = f2bf(a2[r]);
        st[rr + 3 * 16] = f2bf(a3[r]);
    }
    #pragma unroll
    for (int i = 0; i < 4; ++i) {
        int row = base + i * 4 + q;
        if (row < N_NODES) {
            uint2 v = *(const uint2*)&st[(i * 4 + q) * 72 + l16 * 4];
            *(uint2*)(o1 + (size_t)row * 64 + l16 * 4) = v;
        }
    }
}

// ---------------------------------------------------------------------------
// SpMM2: out(fp32) = A @ o1(bf16). 8 lanes/row x uint4, 8 rows/wave,
// 32 rows/block, grid 3125 exact. No LDS.
// ---------------------------------------------------------------------------
__global__ __launch_bounds__(256) void spmm_out(const int* __restrict__ colind,
                                                const float* __restrict__ vals,
                                                const unsigned short* __restrict__ B,
                                                float* __restrict__ out)
{
    const int tid  = threadIdx.x;
    const int lane = tid & 63;
    const int wid  = tid >> 6;
    const int rl   = lane >> 3;
    const int j8   = lane & 7;
    const int row  = blockIdx.x * 32 + wid * 8 + rl;   // 3125*32 = 100000 exact

    float acc[8] = {0.f,0.f,0.f,0.f,0.f,0.f,0.f,0.f};
    gather_row8(B, colind + (size_t)row * DEG, vals + (size_t)row * DEG, j8, acc);

    float4 lo; lo.x = acc[0]; lo.y = acc[1]; lo.z = acc[2]; lo.w = acc[3];
    float4 hi; hi.x = acc[4]; hi.y = acc[5]; hi.z = acc[6]; hi.w = acc[7];
    float* op = out + (size_t)row * 64 + j8 * 8;
    *(float4*)op       = lo;
    *(float4*)(op + 4) = hi;
}

extern "C" void kernel_launch(void* const* d_in, const int* in_sizes, int n_in,
                              void* d_out, int out_size, void* d_ws, size_t ws_size,
                              hipStream_t stream) {
    const float* X      = (const float*)d_in[0];   // [N,256]
    const float* W1     = (const float*)d_in[1];   // [256,64]
    const float* W2     = (const float*)d_in[2];   // [64,64]
    const float* vals   = (const float*)d_in[3];   // [NNZ]
    // d_in[4] = rowptr (fixed degree, unused)
    const int*   colind = (const int*)d_in[5];     // [NNZ]
    float*       out    = (float*)d_out;           // [N,64] fp32

    unsigned short* h  = (unsigned short*)d_ws;        // [N,64] bf16
    unsigned short* o1 = h + (size_t)N_NODES * 64;     // [N,64] bf16 (no alias)

    hipLaunchKernelGGL(gemm1_k256, dim3(G1_BLOCKS), dim3(256), 0, stream, X, W1, h);
    hipLaunchKernelGGL(spmm_gemm2, dim3(NG64), dim3(256), 0, stream,
                       colind, vals, h, W2, o1);
    hipLaunchKernelGGL(spmm_out, dim3(N_NODES / 32), dim3(256), 0, stream,
                       colind, vals, o1, out);
}

// Round 8
// 230.526 us; speedup vs baseline: 2.2644x; 1.0001x over previous
//
#include <hip/hip_runtime.h>
#include <hip/hip_bf16.h>

#define N_NODES 100000
#define DEG 16
#define NT16 6250             // 16-row tiles (100000/16)
#define NG64 1563             // 64-row groups (ceil)
#define G1_BLOCKS 782         // 3128 waves -> exactly <=2 tiles/wave
#define G1_WSTRIDE (G1_BLOCKS * 4)

typedef __attribute__((ext_vector_type(8))) short short8;   // 8 bf16
typedef __attribute__((ext_vector_type(4))) float f32x4;
// raw ext-vector types for __builtin_nontemporal_* (HIP struct vectors not accepted)
typedef __attribute__((ext_vector_type(4))) float f4raw;
typedef __attribute__((ext_vector_type(4))) int   i4raw;
typedef __attribute__((ext_vector_type(4))) unsigned u4raw;

__device__ inline unsigned short f2bf(float f) {
    union { float f; unsigned u; } v; v.f = f;
    unsigned u = v.u;
    u += 0x7FFFu + ((u >> 16) & 1u);    // RNE
    return (unsigned short)(u >> 16);
}
__device__ inline unsigned pk2bf(float a, float b) {        // HW v_cvt_pk_bf16_f32 (RNE)
    union { __hip_bfloat162 b2; unsigned u; } v;
    v.b2 = __float22bfloat162_rn(make_float2(a, b));
    return v.u;
}
__device__ inline float bflo(unsigned u) {
    union { unsigned u; float f; } v; v.u = u << 16; return v.f;
}
__device__ inline float bfhi(unsigned u) {
    union { unsigned u; float f; } v; v.u = u & 0xFFFF0000u; return v.f;
}

// ---------------------------------------------------------------------------
// GEMM1: h[M,64](bf16) = X[M,256](fp32) @ W1[256,64](fp32).
// Half-tile software pipeline (spill-free, verified R6/R7); 2 tiles/wave.
// X loads are NON-TEMPORAL: X is stream-once; keep L2 free for the h writes
// so spmm_gemm2 finds h resident. LDS = 41 KB -> 3 blocks/CU.
// ---------------------------------------------------------------------------
__global__ __launch_bounds__(256) void gemm1_k256(const float* __restrict__ X,
                                                  const float* __restrict__ W1,
                                                  unsigned short* __restrict__ h)
{
    __shared__ unsigned short wfrag[256 * 64];      // 32 KB, B-fragment order
    __shared__ unsigned short estage[4][16 * 72];   //  9 KB, per-wave epilogue

    const int tid  = threadIdx.x;
    const int lane = tid & 63;
    const int wid  = tid >> 6;
    const int q    = lane >> 4;
    const int l16  = lane & 15;

    // ---- W1 staging: rows kg*4..+3, cols cq*16..+15 per thread ----
    {
        const int kg = tid >> 2;          // 0..63
        const int cq = tid & 3;           // col quarter
        float4 wr[16];
        #pragma unroll
        for (int r = 0; r < 4; ++r)
            #pragma unroll
            for (int i = 0; i < 4; ++i)
                wr[r * 4 + i] = *(const float4*)(W1 + (kg * 4 + r) * 64 + cq * 16 + i * 4);
        const int kb  = kg >> 3;
        const int lnr = (((kg * 4) >> 3) & 3) * 16;
        const int jb  = (kg * 4) & 7;
        #pragma unroll
        for (int c = 0; c < 16; ++c) {
            ushort4 w4;
            #pragma unroll
            for (int r = 0; r < 4; ++r) {
                float4 v = wr[r * 4 + (c >> 2)];
                float  f = ((c & 3) == 0) ? v.x : ((c & 3) == 1) ? v.y :
                           ((c & 3) == 2) ? v.z : v.w;
                ((unsigned short*)&w4)[r] = f2bf(f);
            }
            *(ushort4*)&wfrag[(((kb * 4) + cq) * 64 + lnr + c) * 8 + jb] = w4;
        }
    }
    __syncthreads();

    const int bpidx = (((l16 << 2) | q) << 2);   // source lane * 4 for bpermute
    const size_t xoff = (size_t)(lane >> 2) * 256 + (lane & 3) * 8;

    int t = blockIdx.x * 4 + wid;

    f4raw pa[8];                                  // half0: kb = 0..3
    {
        const float* xb = X + (size_t)t * 16 * 256 + xoff;
        #pragma unroll
        for (int kb = 0; kb < 4; ++kb) {
            pa[2 * kb]     = __builtin_nontemporal_load((const f4raw*)(xb + kb * 32));
            pa[2 * kb + 1] = __builtin_nontemporal_load((const f4raw*)(xb + kb * 32 + 4));
        }
    }

    while (t < NT16) {
        const float* xb = X + (size_t)t * 16 * 256 + xoff;
        f4raw pb[8];                              // half1 loads in flight
        #pragma unroll
        for (int kb = 4; kb < 8; ++kb) {
            pb[2 * (kb - 4)]     = __builtin_nontemporal_load((const f4raw*)(xb + kb * 32));
            pb[2 * (kb - 4) + 1] = __builtin_nontemporal_load((const f4raw*)(xb + kb * 32 + 4));
        }

        f32x4 a0 = {0,0,0,0}, a1 = {0,0,0,0}, a2 = {0,0,0,0}, a3 = {0,0,0,0};

        #pragma unroll
        for (int kb = 0; kb < 4; ++kb) {          // compute half0
            union { int u[4]; short8 s; } uu;
            uu.u[0] = __builtin_amdgcn_ds_bpermute(bpidx, (int)pk2bf(pa[2*kb].x,   pa[2*kb].y));
            uu.u[1] = __builtin_amdgcn_ds_bpermute(bpidx, (int)pk2bf(pa[2*kb].z,   pa[2*kb].w));
            uu.u[2] = __builtin_amdgcn_ds_bpermute(bpidx, (int)pk2bf(pa[2*kb+1].x, pa[2*kb+1].y));
            uu.u[3] = __builtin_amdgcn_ds_bpermute(bpidx, (int)pk2bf(pa[2*kb+1].z, pa[2*kb+1].w));
            const short8* wp = (const short8*)&wfrag[(size_t)((kb * 4) * 64 + lane) * 8];
            a0 = __builtin_amdgcn_mfma_f32_16x16x32_bf16(uu.s, wp[0 * 64], a0, 0, 0, 0);
            a1 = __builtin_amdgcn_mfma_f32_16x16x32_bf16(uu.s, wp[1 * 64], a1, 0, 0, 0);
            a2 = __builtin_amdgcn_mfma_f32_16x16x32_bf16(uu.s, wp[2 * 64], a2, 0, 0, 0);
            a3 = __builtin_amdgcn_mfma_f32_16x16x32_bf16(uu.s, wp[3 * 64], a3, 0, 0, 0);
        }

        const int tn = t + G1_WSTRIDE;            // next tile's half0 in flight
        if (tn < NT16) {
            const float* xn = X + (size_t)tn * 16 * 256 + xoff;
            #pragma unroll
            for (int kb = 0; kb < 4; ++kb) {
                pa[2 * kb]     = __builtin_nontemporal_load((const f4raw*)(xn + kb * 32));
                pa[2 * kb + 1] = __builtin_nontemporal_load((const f4raw*)(xn + kb * 32 + 4));
            }
        }

        #pragma unroll
        for (int kb = 4; kb < 8; ++kb) {          // compute half1
            const int i = kb - 4;
            union { int u[4]; short8 s; } uu;
            uu.u[0] = __builtin_amdgcn_ds_bpermute(bpidx, (int)pk2bf(pb[2*i].x,   pb[2*i].y));
            uu.u[1] = __builtin_amdgcn_ds_bpermute(bpidx, (int)pk2bf(pb[2*i].z,   pb[2*i].w));
            uu.u[2] = __builtin_amdgcn_ds_bpermute(bpidx, (int)pk2bf(pb[2*i+1].x, pb[2*i+1].y));
            uu.u[3] = __builtin_amdgcn_ds_bpermute(bpidx, (int)pk2bf(pb[2*i+1].z, pb[2*i+1].w));
            const short8* wp = (const short8*)&wfrag[(size_t)((kb * 4) * 64 + lane) * 8];
            a0 = __builtin_amdgcn_mfma_f32_16x16x32_bf16(uu.s, wp[0 * 64], a0, 0, 0, 0);
            a1 = __builtin_amdgcn_mfma_f32_16x16x32_bf16(uu.s, wp[1 * 64], a1, 0, 0, 0);
            a2 = __builtin_amdgcn_mfma_f32_16x16x32_bf16(uu.s, wp[2 * 64], a2, 0, 0, 0);
            a3 = __builtin_amdgcn_mfma_f32_16x16x32_bf16(uu.s, wp[3 * 64], a3, 0, 0, 0);
        }

        // epilogue: D[q*4+r][ct*16+l16] -> bf16 rows via per-wave LDS
        unsigned short* st = estage[wid];
        #pragma unroll
        for (int r = 0; r < 4; ++r) {
            int rr = (q * 4 + r) * 72 + l16;
            st[rr + 0 * 16] = f2bf(a0[r]);
            st[rr + 1 * 16] = f2bf(a1[r]);
            st[rr + 2 * 16] = f2bf(a2[r]);
            st[rr + 3 * 16] = f2bf(a3[r]);
        }
        #pragma unroll
        for (int i = 0; i < 4; ++i) {
            int row = i * 4 + q;
            uint2 v = *(const uint2*)&st[row * 72 + l16 * 4];
            *(uint2*)(h + (size_t)(t * 16 + row) * 64 + l16 * 4) = v;   // cached: spmm1 reuses
        }
        t = tn;
    }
}

// ---------------------------------------------------------------------------
// Row gather, 8 lanes/row x uint4; colind/vals loads NON-TEMPORAL (stream-once)
// so they don't evict gather lines from L2.
// ---------------------------------------------------------------------------
__device__ inline void gather_row8(const unsigned short* __restrict__ B,
                                   const int* __restrict__ ci,
                                   const float* __restrict__ vv,
                                   int j8, float* __restrict__ acc)
{
    #pragma unroll
    for (int b = 0; b < 2; ++b) {
        i4raw c0 = __builtin_nontemporal_load((const i4raw*)ci + 2 * b);
        i4raw c1 = __builtin_nontemporal_load((const i4raw*)ci + 2 * b + 1);
        f4raw v0 = __builtin_nontemporal_load((const f4raw*)vv + 2 * b);
        f4raw v1 = __builtin_nontemporal_load((const f4raw*)vv + 2 * b + 1);
        uint4 g0 = *(const uint4*)(B + (size_t)c0.x * 64 + j8 * 8);
        uint4 g1 = *(const uint4*)(B + (size_t)c0.y * 64 + j8 * 8);
        uint4 g2 = *(const uint4*)(B + (size_t)c0.z * 64 + j8 * 8);
        uint4 g3 = *(const uint4*)(B + (size_t)c0.w * 64 + j8 * 8);
        uint4 g4 = *(const uint4*)(B + (size_t)c1.x * 64 + j8 * 8);
        uint4 g5 = *(const uint4*)(B + (size_t)c1.y * 64 + j8 * 8);
        uint4 g6 = *(const uint4*)(B + (size_t)c1.z * 64 + j8 * 8);
        uint4 g7 = *(const uint4*)(B + (size_t)c1.w * 64 + j8 * 8);
#define ACC8(g, s) \
        acc[0] += (s) * bflo((g).x); acc[1] += (s) * bfhi((g).x); \
        acc[2] += (s) * bflo((g).y); acc[3] += (s) * bfhi((g).y); \
        acc[4] += (s) * bflo((g).z); acc[5] += (s) * bfhi((g).z); \
        acc[6] += (s) * bflo((g).w); acc[7] += (s) * bfhi((g).w);
        ACC8(g0, v0.x) ACC8(g1, v0.y) ACC8(g2, v0.z) ACC8(g3, v0.w)
        ACC8(g4, v1.x) ACC8(g5, v1.y) ACC8(g6, v1.z) ACC8(g7, v1.w)
#undef ACC8
    }
}

// ---------------------------------------------------------------------------
// Fused SpMM1 + ReLU + GEMM2: o1 = bf16( relu(A @ h) @ W2 ).  17 KB LDS.
// ---------------------------------------------------------------------------
__global__ __launch_bounds__(256) void spmm_gemm2(const int* __restrict__ colind,
                                                  const float* __restrict__ vals,
                                                  const unsigned short* __restrict__ h,
                                                  const float* __restrict__ W2,
                                                  unsigned short* __restrict__ o1)
{
    __shared__ unsigned short wfrag2[64 * 64];      // 8 KB
    __shared__ unsigned short stage[4][16 * 72];    // 9 KB

    const int tid  = threadIdx.x;
    const int lane = tid & 63;
    const int wid  = tid >> 6;
    const int q    = lane >> 4;
    const int l16  = lane & 15;

    // ---- W2 staging ----
    {
        const int r4 = tid >> 2;
        const int qt = tid & 3;
        float4 wr[4];
        #pragma unroll
        for (int i = 0; i < 4; ++i)
            wr[i] = *(const float4*)(W2 + r4 * 64 + qt * 16 + i * 4);
        const int kb  = r4 >> 5;
        const int j   = r4 & 7;
        const int lnr = ((r4 >> 3) & 3) * 16;
        #pragma unroll
        for (int c = 0; c < 16; ++c) {
            float f = ((c & 3) == 0) ? wr[c >> 2].x :
                      ((c & 3) == 1) ? wr[c >> 2].y :
                      ((c & 3) == 2) ? wr[c >> 2].z : wr[c >> 2].w;
            wfrag2[(((kb * 4) + qt) * 64 + lnr + c) * 8 + j] = f2bf(f);
        }
    }
    __syncthreads();

    const int base = blockIdx.x * 64 + wid * 16;    // grid 1563 covers 100032
    unsigned short* st = stage[wid];
    const int rl = lane >> 3;
    const int j8 = lane & 7;

    #pragma unroll
    for (int p = 0; p < 2; ++p) {
        int lr  = p * 8 + rl;
        int row = base + lr;
        int rc  = row < N_NODES ? row : N_NODES - 1;
        float acc[8] = {0.f,0.f,0.f,0.f,0.f,0.f,0.f,0.f};
        gather_row8(h, colind + (size_t)rc * DEG, vals + (size_t)rc * DEG, j8, acc);
        uint4 pk;
        pk.x = pk2bf(fmaxf(acc[0], 0.f), fmaxf(acc[1], 0.f));
        pk.y = pk2bf(fmaxf(acc[2], 0.f), fmaxf(acc[3], 0.f));
        pk.z = pk2bf(fmaxf(acc[4], 0.f), fmaxf(acc[5], 0.f));
        pk.w = pk2bf(fmaxf(acc[6], 0.f), fmaxf(acc[7], 0.f));
        *(uint4*)&st[lr * 72 + j8 * 8] = pk;
    }
    // wave-private LDS slice: DS ops in-order per wave, no barrier needed

    f32x4 a0 = {0,0,0,0}, a1 = {0,0,0,0}, a2 = {0,0,0,0}, a3 = {0,0,0,0};
    #pragma unroll
    for (int kb = 0; kb < 2; ++kb) {
        short8 af = *(const short8*)&st[l16 * 72 + kb * 32 + q * 8];
        const short8* wp = (const short8*)&wfrag2[(size_t)((kb * 4) * 64 + lane) * 8];
        a0 = __builtin_amdgcn_mfma_f32_16x16x32_bf16(af, wp[0 * 64], a0, 0, 0, 0);
        a1 = __builtin_amdgcn_mfma_f32_16x16x32_bf16(af, wp[1 * 64], a1, 0, 0, 0);
        a2 = __builtin_amdgcn_mfma_f32_16x16x32_bf16(af, wp[2 * 64], a2, 0, 0, 0);
        a3 = __builtin_amdgcn_mfma_f32_16x16x32_bf16(af, wp[3 * 64], a3, 0, 0, 0);
    }
    #pragma unroll
    for (int r = 0; r < 4; ++r) {
        int rr = (q * 4 + r) * 72 + l16;
        st[rr + 0 * 16] = f2bf(a0[r]);
        st[rr + 1 * 16] = f2bf(a1[r]);
        st[rr + 2 * 16] = f2bf(a2[r]);
        st[rr + 3 * 16] = f2bf(a3[r]);
    }
    #pragma unroll
    for (int i = 0; i < 4; ++i) {
        int row = base + i * 4 + q;
        if (row < N_NODES) {
            uint2 v = *(const uint2*)&st[(i * 4 + q) * 72 + l16 * 4];
            *(uint2*)(o1 + (size_t)row * 64 + l16 * 4) = v;   // cached: spmm2 reuses
        }
    }
}

// ---------------------------------------------------------------------------
// SpMM2: out(fp32) = A @ o1(bf16). Non-temporal out stores (never re-read)
// keep L2 free for o1 gathers. Grid 3125 exact, no LDS.
// ---------------------------------------------------------------------------
__global__ __launch_bounds__(256) void spmm_out(const int* __restrict__ colind,
                                                const float* __restrict__ vals,
                                                const unsigned short* __restrict__ B,
                                                float* __restrict__ out)
{
    const int tid  = threadIdx.x;
    const int lane = tid & 63;
    const int wid  = tid >> 6;
    const int rl   = lane >> 3;
    const int j8   = lane & 7;
    const int row  = blockIdx.x * 32 + wid * 8 + rl;   // 3125*32 = 100000 exact

    float acc[8] = {0.f,0.f,0.f,0.f,0.f,0.f,0.f,0.f};
    gather_row8(B, colind + (size_t)row * DEG, vals + (size_t)row * DEG, j8, acc);

    f4raw lo = { acc[0], acc[1], acc[2], acc[3] };
    f4raw hi = { acc[4], acc[5], acc[6], acc[7] };
    float* op = out + (size_t)row * 64 + j8 * 8;
    __builtin_nontemporal_store(lo, (f4raw*)op);
    __builtin_nontemporal_store(hi, (f4raw*)(op + 4));
}

extern "C" void kernel_launch(void* const* d_in, const int* in_sizes, int n_in,
                              void* d_out, int out_size, void* d_ws, size_t ws_size,
                              hipStream_t stream) {
    const float* X      = (const float*)d_in[0];   // [N,256]
    const float* W1     = (const float*)d_in[1];   // [256,64]
    const float* W2     = (const float*)d_in[2];   // [64,64]
    const float* vals   = (const float*)d_in[3];   // [NNZ]
    // d_in[4] = rowptr (fixed degree, unused)
    const int*   colind = (const int*)d_in[5];     // [NNZ]
    float*       out    = (float*)d_out;           // [N,64] fp32

    unsigned short* h  = (unsigned short*)d_ws;        // [N,64] bf16
    unsigned short* o1 = h + (size_t)N_NODES * 64;     // [N,64] bf16 (no alias)

    hipLaunchKernelGGL(gemm1_k256, dim3(G1_BLOCKS), dim3(256), 0, stream, X, W1, h);
    hipLaunchKernelGGL(spmm_gemm2, dim3(NG64), dim3(256), 0, stream,
                       colind, vals, h, W2, o1);
    hipLaunchKernelGGL(spmm_out, dim3(N_NODES / 32), dim3(256), 0, stream,
                       colind, vals, o1, out);
}